// Round 10
// baseline (538.435 us; speedup 1.0000x reference)
//
#include <hip/hip_runtime.h>

// Problem constants (from reference)
#define NCH   52            // NC
#define NSs   128           // NS (scan length)
#define NRAYS 64
#define INNER 64            // NR*NT = 4*16
#define XS    (3*NCH*INNER) // per-s stride in x       = 9984 floats
#define ZS    (2*NCH*INNER) // per-s stride in z_vals  = 6656 floats
#define NOUT  (NRAYS*NCH*INNER)  // 212992 complex outputs
#define NCG   13            // channel groups of 4 (52/4)
#define NBLK  (NRAYS*NCG)   // 832 blocks x 256 thr = 212992 threads

// Recurrence (reference semantics, verified PASSED in round 9):
//   f[t]   = (1-alpha[t]) * e^{-i*w*(z[t+1]-z[t])} + 1e-10   (real-part add)
//   P[s]   = prod_{t<s} f[t],  P[0] = 0
//   out    = sum_s ch[s] * (ampc/z[s]) * alpha[s] * P[s]
//
// THIS VERSION: float4-contiguous loads + the verified 4-way s-segmentation.
// Evidence: render kernel pinned at ~145us (3.0 TB/s) across ILP- and
// TLP-varied kernels, while the harness fills hit 6.6 TB/s. Remaining
// difference: fills move 1KB contiguous per wave instruction (16B/lane);
// we moved 256B (4B/lane dword). Fix the granularity:
//   - thread owns 4 consecutive inner positions (one float4) of ONE channel
//   - wave = 4 ADJACENT channels x 16 float4-lanes -> each global_load_dwordx4
//     covers 4*64 floats = 1KB CONTIGUOUS (channels adjacent in x layout)
//   - block = 4 waves = 4 s-segments of 32 steps (round-9 LDS combine:
//     out = sum0 + F0*(sum1 + F1*(sum2 + F2*sum3)), pure f32 reassociation)
// Grid 832 x 256 -> 3328 waves = 13 waves/CU. Same FLOPs, same bytes.
//
// Output layout: PLANAR float32 — [all 212992 reals][all 212992 imags]
__global__ __launch_bounds__(256) void render_kernel(
    const float* __restrict__ x,
    const float* __restrict__ zv,
    const float* __restrict__ fc,
    float* __restrict__ out)
{
    const int b    = blockIdx.x;
    const int r    = b / NCG;
    const int cg   = b - r * NCG;
    const int t    = threadIdx.x;
    const int seg  = t >> 6;            // wave id = s-segment (0..3)
    const int lane = t & 63;
    const int chof = lane >> 4;         // 0..3: channel within group
    const int idx  = lane & 15;         // float4 position over inner
    const int c    = cg * 4 + chof;

    // float4-unit strides
    const int XS4 = XS / 4;             // 2496
    const int ZS4 = ZS / 4;             // 1664
    const int P4  = (NCH * INNER) / 4;  // 832 (plane offset in x)

    const float4* xp = (const float4*)(x  + (size_t)r * NSs * XS + c * INNER) + idx;
    const float4* zp = (const float4*)(zv + (size_t)r * NSs * ZS + c * INNER) + idx;

    const double C_L    = 299792458.0;
    const double PI_D   = 3.14159265358979323846;
    const float  fcd    = fc[NCH + c];
    const double fc_rev = (double)fcd * 1.0e9 / C_L;   // revolutions per unit dist
    const float  ampc   = (float)(C_L / ((double)fcd * 1.0e9 * 4.0 * PI_D));

    // per-chain state (chains j = inner idx*4 + j)
    float Pre[4], Pim[4], are[4], aim[4], zc[4];
    int s = seg * 32;

    {
        float4 z0 = zp[(size_t)s * ZS4];
        zc[0] = z0.x; zc[1] = z0.y; zc[2] = z0.z; zc[3] = z0.w;
    }
#pragma unroll
    for (int j = 0; j < 4; ++j) { are[j] = 0.0f; aim[j] = 0.0f; }

    if (seg == 0) {
        // s = 0: P[0] = 0 -> no contribution; build f[0] into Q.
        float4 z1  = zp[ZS4];
        float4 ar0 = xp[2 * P4];
        float zn[4] = { z1.x, z1.y, z1.z, z1.w };
        float a0[4] = { ar0.x, ar0.y, ar0.z, ar0.w };
#pragma unroll
        for (int j = 0; j < 4; ++j) {
            float oma = __expf(-a0[j]);            // (1 - alpha[0])
            double u  = fc_rev * (double)(zn[j] - zc[j]);
            u -= floor(u);                         // fractional revolutions
            float uf = (float)u;
            float sn = __builtin_amdgcn_sinf(uf);  // sin(2*pi*u)
            float cs = __builtin_amdgcn_cosf(uf);
            Pre[j] = fmaf(oma, cs, 1e-10f);
            Pim[j] = -oma * sn;
            zc[j]  = zn[j];
        }
        s = 1;
    } else {
#pragma unroll
        for (int j = 0; j < 4; ++j) { Pre[j] = 1.0f; Pim[j] = 0.0f; }
    }

    const int send = (seg + 1) * 32;    // exclusive end

#pragma unroll 2
    for (; s < send; ++s) {
        // 1KB-contiguous per wave instruction: 4 adjacent channels x 256B
        float4 xre4 = xp[(size_t)s * XS4];
        float4 xim4 = xp[(size_t)s * XS4 + P4];
        float4 ar4  = xp[(size_t)s * XS4 + 2 * P4];
        int    sn_i = (s + 1 < NSs) ? (s + 1) : (NSs - 1); // clamp: f[127] unused
        float4 z4   = zp[(size_t)sn_i * ZS4];

        float xr[4] = { xre4.x, xre4.y, xre4.z, xre4.w };
        float xi[4] = { xim4.x, xim4.y, xim4.z, xim4.w };
        float aa[4] = { ar4.x,  ar4.y,  ar4.z,  ar4.w  };
        float zn[4] = { z4.x,   z4.y,   z4.z,   z4.w   };

#pragma unroll
        for (int j = 0; j < 4; ++j) {
            // contribution for s: ch * amp_decay * (alpha * Q)
            float oma   = __expf(-aa[j]);          // (1 - alpha)
            float alpha = 1.0f - oma;
            float amp   = ampc * __builtin_amdgcn_rcpf(zc[j]);
            float k     = alpha * amp;
            float cre   = k * Pre[j];
            float cim   = k * Pim[j];
            are[j] = fmaf(xr[j], cre, fmaf(-xi[j], cim, are[j]));
            aim[j] = fmaf(xr[j], cim, fmaf( xi[j], cre, aim[j]));

            // fold f[s] into Q
            double u = fc_rev * (double)(zn[j] - zc[j]);
            u -= floor(u);
            float uf = (float)u;
            float sn = __builtin_amdgcn_sinf(uf);
            float cs = __builtin_amdgcn_cosf(uf);
            float fre = fmaf(oma, cs, 1e-10f);
            float fim = -oma * sn;
            float nre = Pre[j] * fre - Pim[j] * fim;
            float nim = fmaf(Pre[j], fim, Pim[j] * fre);
            Pre[j] = nre;
            Pim[j] = nim;
            zc[j]  = zn[j];
        }
    }

    // ---- combine the 4 segments in LDS (round-9 scheme, float4-wide) ----
    // comb[k-1][lane][q]: q=0 sum_re, 1 sum_im, 2 F_re, 3 F_im for segment k
    __shared__ float4 comb[3][64][4];
    if (seg > 0) {
        comb[seg - 1][lane][0] = make_float4(are[0], are[1], are[2], are[3]);
        comb[seg - 1][lane][1] = make_float4(aim[0], aim[1], aim[2], aim[3]);
        comb[seg - 1][lane][2] = make_float4(Pre[0], Pre[1], Pre[2], Pre[3]);
        comb[seg - 1][lane][3] = make_float4(Pim[0], Pim[1], Pim[2], Pim[3]);
    }
    __syncthreads();

    if (seg == 0) {
        float ore[4], oim[4];
        {   // o = sum3
            float4 sr = comb[2][lane][0], si = comb[2][lane][1];
            ore[0] = sr.x; ore[1] = sr.y; ore[2] = sr.z; ore[3] = sr.w;
            oim[0] = si.x; oim[1] = si.y; oim[2] = si.z; oim[3] = si.w;
        }
#pragma unroll
        for (int k = 2; k >= 1; --k) {  // o = sum_k + F_k * o
            float4 sr = comb[k - 1][lane][0], si = comb[k - 1][lane][1];
            float4 fr = comb[k - 1][lane][2], fi = comb[k - 1][lane][3];
            float srr[4] = { sr.x, sr.y, sr.z, sr.w };
            float sii[4] = { si.x, si.y, si.z, si.w };
            float frr[4] = { fr.x, fr.y, fr.z, fr.w };
            float fii[4] = { fi.x, fi.y, fi.z, fi.w };
#pragma unroll
            for (int j = 0; j < 4; ++j) {
                float tr = srr[j] + frr[j] * ore[j] - fii[j] * oim[j];
                float ti = sii[j] + frr[j] * oim[j] + fii[j] * ore[j];
                ore[j] = tr; oim[j] = ti;
            }
        }
#pragma unroll
        for (int j = 0; j < 4; ++j) {   // o = sum0 + F0 * o (registers)
            float tr = are[j] + Pre[j] * ore[j] - Pim[j] * oim[j];
            float ti = aim[j] + Pre[j] * oim[j] + Pim[j] * ore[j];
            ore[j] = tr; oim[j] = ti;
        }

        const int obase = (r * NCH + c) * INNER + idx * 4;
        *(float4*)(out + obase)        = make_float4(ore[0], ore[1], ore[2], ore[3]);
        *(float4*)(out + NOUT + obase) = make_float4(oim[0], oim[1], oim[2], oim[3]);
    }
}

extern "C" void kernel_launch(void* const* d_in, const int* in_sizes, int n_in,
                              void* d_out, int out_size, void* d_ws, size_t ws_size,
                              hipStream_t stream) {
    const float* x  = (const float*)d_in[0];
    const float* zv = (const float*)d_in[1];
    const float* fc = (const float*)d_in[2];
    float* out = (float*)d_out;

    render_kernel<<<NBLK, 256, 0, stream>>>(x, zv, fc, out);
}